// Round 5
// baseline (338.186 us; speedup 1.0000x reference)
//
#include <hip/hip_runtime.h>
#include <hip/hip_bf16.h>

typedef float  f32x4 __attribute__((ext_vector_type(4)));
typedef short  s16x8 __attribute__((ext_vector_type(8)));
typedef __hip_bfloat16 bf16;

#define BDIM 32
#define TDIM 2048
#define HDIM 1024
#define FDIM 1024
#define MTOT (BDIM*TDIM)   // 65536 rows of keys

// direct global->LDS DMA, 16B per lane; lds dest must be wave-uniform base
#define GLOAD16(gp, lp) __builtin_amdgcn_global_load_lds(                     \
    (const __attribute__((address_space(1))) void*)(gp),                      \
    (__attribute__((address_space(3))) void*)(lp), 16, 0, 0)

#define MFMA_BF16 __builtin_amdgcn_mfma_f32_16x16x32_bf16

// ---------------------------------------------------------------------------
// f32 -> bf16 elementwise convert
// ---------------------------------------------------------------------------
__global__ __launch_bounds__(256) void cvt_bf16_kernel(
    const float* __restrict__ src, bf16* __restrict__ dst, int n8)
{
    int i = blockIdx.x * 256 + threadIdx.x;
    const int stride = gridDim.x * 256;
    for (; i < n8; i += stride) {
        const f32x4 a = ((const f32x4*)src)[2 * i];
        const f32x4 b = ((const f32x4*)src)[2 * i + 1];
        union { bf16 h[8]; s16x8 v; } u;
        #pragma unroll
        for (int j = 0; j < 4; ++j) {
            u.h[j]     = __float2bfloat16(a[j]);
            u.h[4 + j] = __float2bfloat16(b[j]);
        }
        ((s16x8*)dst)[i] = u.v;
    }
}

// ---------------------------------------------------------------------------
// Kernel 1: q_eff[b,o] = sum_h query[b,h]*Wa_w[o,h] + Wa_b[o] + Ua_b[o]
// ---------------------------------------------------------------------------
__global__ __launch_bounds__(256) void qeff_kernel(
    const float* __restrict__ query, const float* __restrict__ Wa_w,
    const float* __restrict__ Wa_b,  const float* __restrict__ Ua_b,
    float* __restrict__ qe)
{
    const int lane = threadIdx.x & 63;
    const int gw   = blockIdx.x * 4 + (threadIdx.x >> 6);
    const int b    = gw >> 10;
    const int o    = gw & 1023;
    const float* qp = query + (size_t)b * HDIM;
    const float* wp = Wa_w  + (size_t)o * HDIM;
    float s = 0.f;
    #pragma unroll
    for (int i = 0; i < 16; ++i) {
        const int h = i * 64 + lane;
        s += qp[h] * wp[h];
    }
    #pragma unroll
    for (int off = 32; off > 0; off >>= 1) s += __shfl_down(s, off);
    if (lane == 0) qe[gw] = s + Wa_b[o] + Ua_b[o];
}

// ---------------------------------------------------------------------------
// Kernel 2 (fast): 256x256 / BK=64 / 8-wave bf16 scores GEMM.
// Round-5 schedule: 2 barriers per K-tile, ds_reads INTERLEAVED with MFMA
// (no read/MFMA barrier separation -> LDS pipe overlaps matrix pipe):
//   top:   [buf p ready]  issue all 24 ds_read_b128 (a[8][2], b[4][2])
//          MFMA mf0-3 x nf0-3 (32) -- compiler's partial lgkm waits let these
//          start as soon as a0/b0 land; read completion hides under MFMA
//   mid:   lgkmcnt(0) + s_barrier   (all reads of buf p done block-wide)
//          stage tile t+2 -> buf p  (8 gload_lds; issue hides under Q2)
//          MFMA mf4-7 x nf0-3 (32, registers only)
//   end:   vmcnt(8) + s_barrier     (drains stage(t+1); never 0 until t=14)
// T1 XCD swizzle + T2 st-swizzle (validated r4: conflicts=0) retained verbatim.
// ---------------------------------------------------------------------------
// staging: wave stages subtile s (r_sub=s>>1, ks=s&1) of half-tile h.
// lane l: row-in-subtile = l>>2, physical 16B slot = l&3 holds logical
// colgroup (l&3) ^ (((l>>5)&1)<<1)   [row>>3 = l>>5].
#define STAGE_A(buf_, kb_, h_, s_) GLOAD16(                                    \
    Ab + (size_t)(M0 + (h_)*128 + (((s_)>>1)<<4) + srow) * FDIM               \
       + (kb_) + (((s_)&1)<<5) + scg*8,                                        \
    &As[buf_][((((h_)*8 + ((s_)>>1)) * 2 + ((s_)&1)) << 9)])
#define STAGE_B(buf_, kb_, h_, s_) GLOAD16(                                    \
    Bb + (size_t)(N0 + (h_)*128 + (((s_)>>1)<<4) + srow) * FDIM               \
       + (kb_) + (((s_)&1)<<5) + scg*8,                                        \
    &Bs[buf_][((((h_)*8 + ((s_)>>1)) * 2 + ((s_)&1)) << 9)])

__global__ __launch_bounds__(512, 2) void score_gemm_256_kernel(
    const bf16* __restrict__ Ab, const bf16* __restrict__ Bb,
    const float* __restrict__ qe, const float* __restrict__ Va,
    float* __restrict__ scores)
{
    __shared__ bf16 As[2][16384];   // 64 KB
    __shared__ bf16 Bs[2][16384];   // 64 KB

    const int tid  = threadIdx.x;
    const int lane = tid & 63;
    const int w    = tid >> 6;          // 0..7
    const int wr   = w >> 2;            // 0..1  (m-half)
    const int wc   = w & 3;             // 0..3  (64-col group)

    const int bid   = blockIdx.x;       // 1024 blocks
    const int local = bid >> 3;         // 0..127 per XCD
    const int mt    = (bid & 7) * 32 + (local >> 2);
    const int nt    = local & 3;
    const int M0 = mt * 256, N0 = nt * 256;

    // staging lane constants (pre-swizzled global source)
    const int srow = lane >> 2;
    const int scg  = (lane & 3) ^ (((lane >> 5) & 1) << 1);
    // fragment-read lane constants (swizzled LDS address, same involution)
    const int r    = lane & 15;
    const int q4   = lane >> 4;
    const int roff = r * 32 + ((q4 ^ (((r >> 3) & 1) << 1)) & 3) * 8;

    f32x4 acc[8][4];
    #pragma unroll
    for (int m = 0; m < 8; ++m)
        #pragma unroll
        for (int n = 0; n < 4; ++n) acc[m][n] = (f32x4){0.f, 0.f, 0.f, 0.f};

    // ---- prologue: tile0 -> buf0, tile1 -> buf1 (16 loads); drain tile0.
    STAGE_B(0, 0, 0, w); STAGE_B(0, 0, 0, w + 8);
    STAGE_B(0, 0, 1, w); STAGE_B(0, 0, 1, w + 8);
    STAGE_A(0, 0, 0, w); STAGE_A(0, 0, 0, w + 8);
    STAGE_A(0, 0, 1, w); STAGE_A(0, 0, 1, w + 8);
    STAGE_B(1, 64, 0, w); STAGE_B(1, 64, 0, w + 8);
    STAGE_B(1, 64, 1, w); STAGE_B(1, 64, 1, w + 8);
    STAGE_A(1, 64, 0, w); STAGE_A(1, 64, 0, w + 8);
    STAGE_A(1, 64, 1, w); STAGE_A(1, 64, 1, w + 8);
    asm volatile("s_waitcnt vmcnt(8)" ::: "memory");
    __builtin_amdgcn_s_barrier();

    #pragma unroll 2
    for (int t = 0; t < 16; ++t) {
        const int p = t & 1;
        s16x8 a[8][2], b[4][2];

        // ---- issue ALL fragment reads for tile t (24 x ds_read_b128)
        #pragma unroll
        for (int mf = 0; mf < 8; ++mf)
            #pragma unroll
            for (int ks = 0; ks < 2; ++ks)
                a[mf][ks] = *(const s16x8*)
                    &As[p][(((wr * 8 + mf) * 2 + ks) << 9) + roff];
        #pragma unroll
        for (int nf = 0; nf < 4; ++nf)
            #pragma unroll
            for (int ks = 0; ks < 2; ++ks)
                b[nf][ks] = *(const s16x8*)
                    &Bs[p][(((wc * 4 + nf) * 2 + ks) << 9) + roff];

        // ---- first half: mf0-3 x nf0-3 (reads complete under these MFMAs)
        __builtin_amdgcn_s_setprio(1);
        #pragma unroll
        for (int mf = 0; mf < 4; ++mf)
            #pragma unroll
            for (int nf = 0; nf < 4; ++nf)
                #pragma unroll
                for (int ks = 0; ks < 2; ++ks)
                    acc[mf][nf] = MFMA_BF16(a[mf][ks], b[nf][ks],
                                            acc[mf][nf], 0, 0, 0);
        __builtin_amdgcn_s_setprio(0);

        // ---- mid: all reads of buf p done block-wide -> safe to restage it
        asm volatile("s_waitcnt lgkmcnt(0)" ::: "memory");
        __builtin_amdgcn_s_barrier();
        __builtin_amdgcn_sched_barrier(0);

        if (t + 2 < 16) {
            const int kb = (t + 2) << 6;
            STAGE_B(p, kb, 0, w); STAGE_B(p, kb, 0, w + 8);
            STAGE_B(p, kb, 1, w); STAGE_B(p, kb, 1, w + 8);
            STAGE_A(p, kb, 0, w); STAGE_A(p, kb, 0, w + 8);
            STAGE_A(p, kb, 1, w); STAGE_A(p, kb, 1, w + 8);
        }

        // ---- second half: mf4-7 x nf0-3 (registers only; overlaps staging)
        __builtin_amdgcn_s_setprio(1);
        #pragma unroll
        for (int mf = 4; mf < 8; ++mf)
            #pragma unroll
            for (int nf = 0; nf < 4; ++nf)
                #pragma unroll
                for (int ks = 0; ks < 2; ++ks)
                    acc[mf][nf] = MFMA_BF16(a[mf][ks], b[nf][ks],
                                            acc[mf][nf], 0, 0, 0);
        __builtin_amdgcn_s_setprio(0);

        // ---- end: counted drain (stage(t+1) complete) + barrier
        if (t < 14) {
            asm volatile("s_waitcnt vmcnt(8)" ::: "memory");
            __builtin_amdgcn_s_barrier();
            __builtin_amdgcn_sched_barrier(0);
        } else if (t == 14) {
            asm volatile("s_waitcnt vmcnt(0)" ::: "memory");
            __builtin_amdgcn_s_barrier();
            __builtin_amdgcn_sched_barrier(0);
        }
    }

    // ---- epilogue: score partial = sum_cols Va*tanh(q+e); reduce; atomic.
    // C/D mapping: col = lane&15, row = (lane>>4)*4 + j
    const int b = M0 >> 11;   // 256-row tile never crosses 2048-row batch
    const float* qrow = qe + (size_t)b * HDIM;
    #pragma unroll
    for (int mf = 0; mf < 8; ++mf) {
        float part[4] = {0.f, 0.f, 0.f, 0.f};
        #pragma unroll
        for (int nf = 0; nf < 4; ++nf) {
            const int c    = N0 + wc * 64 + nf * 16 + (lane & 15);
            const float va = Va[c];
            const float qv = qrow[c];
            #pragma unroll
            for (int j = 0; j < 4; ++j) {
                const float x = qv + acc[mf][nf][j];
                const float e = __expf(2.0f * x);
                part[j] += va * (1.0f - 2.0f / (e + 1.0f));   // tanh(x)
            }
        }
        #pragma unroll
        for (int j = 0; j < 4; ++j)
            #pragma unroll
            for (int off = 1; off < 16; off <<= 1)
                part[j] += __shfl_xor(part[j], off);
        if ((lane & 15) == 0) {
            const int rr = M0 + wr * 128 + mf * 16 + (lane >> 4) * 4;
            #pragma unroll
            for (int j = 0; j < 4; ++j) atomicAdd(&scores[rr + j], part[j]);
        }
    }
}

// ---------------------------------------------------------------------------
// Kernel 2 (fallback): reg-staged f32 scores GEMM (round-1 proven).
// ---------------------------------------------------------------------------
__global__ __launch_bounds__(256) void score_gemm_f32_kernel(
    const float* __restrict__ keys, const float* __restrict__ Ua,
    const float* __restrict__ qe,   const float* __restrict__ Va,
    float* __restrict__ scores)
{
    __shared__ bf16 Asf[128][40];
    __shared__ bf16 Bsf[128][40];

    const int tid  = threadIdx.x;
    const int lane = tid & 63;
    const int wid  = tid >> 6;
    const int wr   = wid >> 1, wc = wid & 1;
    const int n0   = blockIdx.x * 128;
    const int m0   = blockIdx.y * 128;

    const int srow  = tid >> 1;
    const int shalf = tid & 1;
    const float* gA = keys + (size_t)(m0 + srow) * FDIM + shalf * 16;
    const float* gB = Ua   + (size_t)(n0 + srow) * FDIM + shalf * 16;

    f32x4 acc[4][4];
    #pragma unroll
    for (int m = 0; m < 4; ++m)
        #pragma unroll
        for (int n = 0; n < 4; ++n) acc[m][n] = (f32x4){0.f, 0.f, 0.f, 0.f};

    float4 ra[4], rbv[4];
    #pragma unroll
    for (int i = 0; i < 4; ++i) {
        ra[i]  = ((const float4*)gA)[i];
        rbv[i] = ((const float4*)gB)[i];
    }

    for (int kt = 0; kt < 32; ++kt) {
        __syncthreads();
        {
            union { bf16 h[16]; s16x8 v[2]; } ua, ub;
            #pragma unroll
            for (int i = 0; i < 4; ++i) {
                const float* fa = (const float*)&ra[i];
                const float* fb = (const float*)&rbv[i];
                #pragma unroll
                for (int j = 0; j < 4; ++j) {
                    ua.h[i*4+j] = __float2bfloat16(fa[j]);
                    ub.h[i*4+j] = __float2bfloat16(fb[j]);
                }
            }
            *(s16x8*)&Asf[srow][shalf*16]     = ua.v[0];
            *(s16x8*)&Asf[srow][shalf*16 + 8] = ua.v[1];
            *(s16x8*)&Bsf[srow][shalf*16]     = ub.v[0];
            *(s16x8*)&Bsf[srow][shalf*16 + 8] = ub.v[1];
        }
        __syncthreads();

        if (kt + 1 < 32) {
            const float* pa = gA + (kt + 1) * 32;
            const float* pb = gB + (kt + 1) * 32;
            #pragma unroll
            for (int i = 0; i < 4; ++i) {
                ra[i]  = ((const float4*)pa)[i];
                rbv[i] = ((const float4*)pb)[i];
            }
        }

        s16x8 af[4], bfr[4];
        #pragma unroll
        for (int m = 0; m < 4; ++m)
            af[m] = *(const s16x8*)&Asf[wr*64 + m*16 + (lane & 15)][(lane >> 4) * 8];
        #pragma unroll
        for (int n = 0; n < 4; ++n)
            bfr[n] = *(const s16x8*)&Bsf[wc*64 + n*16 + (lane & 15)][(lane >> 4) * 8];
        #pragma unroll
        for (int m = 0; m < 4; ++m)
            #pragma unroll
            for (int n = 0; n < 4; ++n)
                acc[m][n] = MFMA_BF16(af[m], bfr[n], acc[m][n], 0, 0, 0);
    }

    const int b = m0 >> 11;
    const float* qrow = qe + (size_t)b * HDIM;
    #pragma unroll
    for (int m = 0; m < 4; ++m) {
        float part[4] = {0.f, 0.f, 0.f, 0.f};
        #pragma unroll
        for (int n = 0; n < 4; ++n) {
            const int c    = n0 + wc*64 + n*16 + (lane & 15);
            const float va = Va[c];
            const float qv = qrow[c];
            #pragma unroll
            for (int j = 0; j < 4; ++j) {
                const float x = qv + acc[m][n][j];
                const float e = __expf(2.0f * x);
                part[j] += va * (1.0f - 2.0f / (e + 1.0f));
            }
        }
        #pragma unroll
        for (int j = 0; j < 4; ++j)
            #pragma unroll
            for (int off = 1; off < 16; off <<= 1)
                part[j] += __shfl_xor(part[j], off);
        if ((lane & 15) == 0) {
            const int rr = m0 + wr*64 + m*16 + (lane >> 4) * 4;
            #pragma unroll
            for (int j = 0; j < 4; ++j) atomicAdd(&scores[rr + j], part[j]);
        }
    }
}

// ---------------------------------------------------------------------------
// Kernel 3: softmax over T=2048, in place. One block per b.
// ---------------------------------------------------------------------------
__global__ __launch_bounds__(256) void softmax_kernel(float* __restrict__ sw)
{
    const int b    = blockIdx.x;
    const int tid  = threadIdx.x;
    const int lane = tid & 63, wid = tid >> 6;
    __shared__ float red[8];

    float v[8];
    float m = -3.4e38f;
    #pragma unroll
    for (int i = 0; i < 8; ++i) {
        v[i] = sw[b * TDIM + i * 256 + tid];
        m = fmaxf(m, v[i]);
    }
    #pragma unroll
    for (int off = 32; off > 0; off >>= 1) m = fmaxf(m, __shfl_xor(m, off));
    if (lane == 0) red[wid] = m;
    __syncthreads();
    m = fmaxf(fmaxf(red[0], red[1]), fmaxf(red[2], red[3]));

    float s = 0.f;
    #pragma unroll
    for (int i = 0; i < 8; ++i) { v[i] = __expf(v[i] - m); s += v[i]; }
    #pragma unroll
    for (int off = 32; off > 0; off >>= 1) s += __shfl_xor(s, off);
    if (lane == 0) red[4 + wid] = s;
    __syncthreads();
    s = (red[4] + red[5]) + (red[6] + red[7]);

    const float inv = 1.0f / s;
    #pragma unroll
    for (int i = 0; i < 8; ++i) sw[b * TDIM + i * 256 + tid] = v[i] * inv;
}

// ---------------------------------------------------------------------------
// Kernel 4: context[b,f] = sum_t w[b,t]*keys[b,t,f].  bf16-keys variant.
// ---------------------------------------------------------------------------
__global__ __launch_bounds__(256) void context_bf16_kernel(
    const bf16* __restrict__ keys, const float* __restrict__ w,
    float* __restrict__ ctx)
{
    const int tc  = blockIdx.x;   // 0..15 (128 t each)
    const int b   = blockIdx.y;
    const int tid = threadIdx.x;
    __shared__ float ws_[128];
    if (tid < 128) ws_[tid] = w[b * TDIM + tc * 128 + tid];
    __syncthreads();

    const bf16* kp = keys + ((size_t)b * TDIM + (size_t)tc * 128) * FDIM + tid * 4;
    float4 acc = {0.f, 0.f, 0.f, 0.f};
    #pragma unroll 8
    for (int t = 0; t < 128; ++t) {
        const short4 kv = *(const short4*)(kp + (size_t)t * FDIM);
        const float wt = ws_[t];
        acc.x += wt * __uint_as_float(((unsigned)(unsigned short)kv.x) << 16);
        acc.y += wt * __uint_as_float(((unsigned)(unsigned short)kv.y) << 16);
        acc.z += wt * __uint_as_float(((unsigned)(unsigned short)kv.z) << 16);
        acc.w += wt * __uint_as_float(((unsigned)(unsigned short)kv.w) << 16);
    }
    float* cp = ctx + (size_t)b * FDIM + tid * 4;
    atomicAdd(cp + 0, acc.x); atomicAdd(cp + 1, acc.y);
    atomicAdd(cp + 2, acc.z); atomicAdd(cp + 3, acc.w);
}

// f32-keys fallback variant
__global__ __launch_bounds__(256) void context_f32_kernel(
    const float* __restrict__ keys, const float* __restrict__ w,
    float* __restrict__ ctx)
{
    const int tc  = blockIdx.x;
    const int b   = blockIdx.y;
    const int tid = threadIdx.x;
    __shared__ float ws_[128];
    if (tid < 128) ws_[tid] = w[b * TDIM + tc * 128 + tid];
    __syncthreads();

    const float* kp = keys + ((size_t)b * TDIM + (size_t)tc * 128) * FDIM + tid * 4;
    float4 acc = {0.f, 0.f, 0.f, 0.f};
    #pragma unroll 8
    for (int t = 0; t < 128; ++t) {
        const float4 kv = *(const float4*)(kp + (size_t)t * FDIM);
        const float wt = ws_[t];
        acc.x += wt * kv.x; acc.y += wt * kv.y;
        acc.z += wt * kv.z; acc.w += wt * kv.w;
    }
    float* cp = ctx + (size_t)b * FDIM + tid * 4;
    atomicAdd(cp + 0, acc.x); atomicAdd(cp + 1, acc.y);
    atomicAdd(cp + 2, acc.z); atomicAdd(cp + 3, acc.w);
}

// ---------------------------------------------------------------------------
extern "C" void kernel_launch(void* const* d_in, const int* in_sizes, int n_in,
                              void* d_out, int out_size, void* d_ws, size_t ws_size,
                              hipStream_t stream)
{
    const float* query = (const float*)d_in[0];
    const float* keys  = (const float*)d_in[1];
    const float* Wa_w  = (const float*)d_in[2];
    const float* Wa_b  = (const float*)d_in[3];
    const float* Ua_w  = (const float*)d_in[4];
    const float* Ua_b  = (const float*)d_in[5];
    const float* Va_w  = (const float*)d_in[6];
    // d_in[7] = Va_b: softmax is shift-invariant -> no effect on outputs.

    float* out = (float*)d_out;
    float* ctx = out;                 // 32*1024 floats; doubles as q_eff scratch
    float* sw  = out + BDIM * HDIM;   // 32*2048 floats; scores -> weights

    const size_t needA = (size_t)MTOT * FDIM * sizeof(bf16);   // 128 MB
    const size_t needB = (size_t)HDIM * FDIM * sizeof(bf16);   //   2 MB
    const bool fast = ws_size >= needA + needB;

    hipMemsetAsync(sw, 0, (size_t)BDIM * TDIM * sizeof(float), stream);
    qeff_kernel<<<dim3(BDIM * HDIM / 4), 256, 0, stream>>>(query, Wa_w, Wa_b, Ua_b, ctx);

    if (fast) {
        bf16* Ab = (bf16*)d_ws;
        bf16* Bb = Ab + (size_t)MTOT * FDIM;
        cvt_bf16_kernel<<<dim3(2048), 256, 0, stream>>>(keys, Ab, MTOT * FDIM / 8);
        cvt_bf16_kernel<<<dim3(512),  256, 0, stream>>>(Ua_w, Bb, HDIM * FDIM / 8);
        score_gemm_256_kernel<<<dim3(1024), 512, 0, stream>>>(Ab, Bb, ctx, Va_w, sw);
        softmax_kernel<<<dim3(BDIM), 256, 0, stream>>>(sw);
        hipMemsetAsync(ctx, 0, (size_t)BDIM * HDIM * sizeof(float), stream);
        context_bf16_kernel<<<dim3(16, BDIM), 256, 0, stream>>>(Ab, sw, ctx);
    } else {
        score_gemm_f32_kernel<<<dim3(HDIM / 128, MTOT / 128), 256, 0, stream>>>(
            keys, Ua_w, ctx, Va_w, sw);
        softmax_kernel<<<dim3(BDIM), 256, 0, stream>>>(sw);
        hipMemsetAsync(ctx, 0, (size_t)BDIM * HDIM * sizeof(float), stream);
        context_f32_kernel<<<dim3(16, BDIM), 256, 0, stream>>>(keys, sw, ctx);
    }
}

// Round 6
// 271.496 us; speedup vs baseline: 1.2456x; 1.2456x over previous
//
#include <hip/hip_runtime.h>
#include <hip/hip_bf16.h>

typedef float  f32x4 __attribute__((ext_vector_type(4)));
typedef short  s16x8 __attribute__((ext_vector_type(8)));
typedef __hip_bfloat16 bf16;

#define BDIM 32
#define TDIM 2048
#define HDIM 1024
#define FDIM 1024
#define MTOT (BDIM*TDIM)   // 65536 rows of keys

// direct global->LDS DMA, 16B per lane; lds dest must be wave-uniform base
#define GLOAD16(gp, lp) __builtin_amdgcn_global_load_lds(                     \
    (const __attribute__((address_space(1))) void*)(gp),                      \
    (__attribute__((address_space(3))) void*)(lp), 16, 0, 0)

#define MFMA_BF16 __builtin_amdgcn_mfma_f32_16x16x32_bf16

// ---------------------------------------------------------------------------
// f32 -> bf16 elementwise convert
// ---------------------------------------------------------------------------
__global__ __launch_bounds__(256) void cvt_bf16_kernel(
    const float* __restrict__ src, bf16* __restrict__ dst, int n8)
{
    int i = blockIdx.x * 256 + threadIdx.x;
    const int stride = gridDim.x * 256;
    for (; i < n8; i += stride) {
        const f32x4 a = ((const f32x4*)src)[2 * i];
        const f32x4 b = ((const f32x4*)src)[2 * i + 1];
        union { bf16 h[8]; s16x8 v; } u;
        #pragma unroll
        for (int j = 0; j < 4; ++j) {
            u.h[j]     = __float2bfloat16(a[j]);
            u.h[4 + j] = __float2bfloat16(b[j]);
        }
        ((s16x8*)dst)[i] = u.v;
    }
}

// ---------------------------------------------------------------------------
// Kernel 1: q_eff[b,o] = sum_h query[b,h]*Wa_w[o,h] + Wa_b[o] + Ua_b[o]
// ---------------------------------------------------------------------------
__global__ __launch_bounds__(256) void qeff_kernel(
    const float* __restrict__ query, const float* __restrict__ Wa_w,
    const float* __restrict__ Wa_b,  const float* __restrict__ Ua_b,
    float* __restrict__ qe)
{
    const int lane = threadIdx.x & 63;
    const int gw   = blockIdx.x * 4 + (threadIdx.x >> 6);
    const int b    = gw >> 10;
    const int o    = gw & 1023;
    const float* qp = query + (size_t)b * HDIM;
    const float* wp = Wa_w  + (size_t)o * HDIM;
    float s = 0.f;
    #pragma unroll
    for (int i = 0; i < 16; ++i) {
        const int h = i * 64 + lane;
        s += qp[h] * wp[h];
    }
    #pragma unroll
    for (int off = 32; off > 0; off >>= 1) s += __shfl_down(s, off);
    if (lane == 0) qe[gw] = s + Wa_b[o] + Ua_b[o];
}

// ---------------------------------------------------------------------------
// Kernel 2 (fast): 256x256 / BK=64 / 8-wave / 8-phase bf16 scores GEMM.
// Round-6: r4's proven phase/MFMA structure (no spills, conflicts=0) with
// TEMPLATE-FAITHFUL staging: 2 gload calls per phase, rotation:
//   P0,P1: A(2i+1)->buf1   [buf1.A free since prev P7]
//   P2,P3: B(2i+2)->buf0   [buf0.B read-complete after P1]
//   P4,P5: A(2i+2)->buf0   [buf0.A read-complete after P2]
//   P6,P7: B(2i+3)->buf1   [buf1.B read-complete after P5]
// Gates (counted, once per K-tile):
//   P3-end: vmcnt(4) -> drains exactly tile 2i+1 (B then A) before P4 reads it
//   P7-end: vmcnt(4) -> drains exactly tile 2i+2 before next P0
// Steady state: 12 outstanding at each gate, invariant "B of next odd tile
// in flight (4)" across iterations; prologue stages B0,A0,B1 + vmcnt(4).
// T1 XCD swizzle + T2 st-swizzle (r4: conflicts=0) retained verbatim.
// ---------------------------------------------------------------------------
// staging: wave stages subtile s (r_sub=s>>1, ks=s&1) of half-tile h.
// lane l: row-in-subtile = l>>2, physical 16B slot = l&3 holds logical
// colgroup (l&3) ^ (((l>>5)&1)<<1)   [row>>3 = l>>5].
#define STAGE_A(buf_, kb_, h_, s_) GLOAD16(                                    \
    Ab + (size_t)(M0 + (h_)*128 + (((s_)>>1)<<4) + srow) * FDIM               \
       + (kb_) + (((s_)&1)<<5) + scg*8,                                        \
    &As[buf_][((((h_)*8 + ((s_)>>1)) * 2 + ((s_)&1)) << 9)])
#define STAGE_B(buf_, kb_, h_, s_) GLOAD16(                                    \
    Bb + (size_t)(N0 + (h_)*128 + (((s_)>>1)<<4) + srow) * FDIM               \
       + (kb_) + (((s_)&1)<<5) + scg*8,                                        \
    &Bs[buf_][((((h_)*8 + ((s_)>>1)) * 2 + ((s_)&1)) << 9)])

__global__ __launch_bounds__(512) void score_gemm_256_kernel(
    const bf16* __restrict__ Ab, const bf16* __restrict__ Bb,
    const float* __restrict__ qe, const float* __restrict__ Va,
    float* __restrict__ scores)
{
    __shared__ bf16 As[2][16384];   // 64 KB
    __shared__ bf16 Bs[2][16384];   // 64 KB

    const int tid  = threadIdx.x;
    const int lane = tid & 63;
    const int w    = tid >> 6;          // 0..7
    const int wr   = w >> 2;            // 0..1  (m-half)
    const int wc   = w & 3;             // 0..3  (64-col group)

    const int bid   = blockIdx.x;       // 1024 blocks
    const int local = bid >> 3;         // 0..127 per XCD
    const int mt    = (bid & 7) * 32 + (local >> 2);
    const int nt    = local & 3;
    const int M0 = mt * 256, N0 = nt * 256;

    // staging lane constants (pre-swizzled global source)
    const int srow = lane >> 2;
    const int scg  = (lane & 3) ^ (((lane >> 5) & 1) << 1);
    // fragment-read lane constants (swizzled LDS address, same involution)
    const int r    = lane & 15;
    const int q4   = lane >> 4;
    const int roff = r * 32 + ((q4 ^ (((r >> 3) & 1) << 1)) & 3) * 8;

    f32x4 acc[8][4];
    #pragma unroll
    for (int m = 0; m < 8; ++m)
        #pragma unroll
        for (int n = 0; n < 4; ++n) acc[m][n] = (f32x4){0.f, 0.f, 0.f, 0.f};

    // ---- prologue: B(t0), A(t0) -> buf0; B(t1) -> buf1 (12 calls).
    // vmcnt(4): t0 complete, B(t1) in flight -> steady-state invariant.
    STAGE_B(0, 0, 0, w); STAGE_B(0, 0, 0, w + 8);
    STAGE_B(0, 0, 1, w); STAGE_B(0, 0, 1, w + 8);
    STAGE_A(0, 0, 0, w); STAGE_A(0, 0, 0, w + 8);
    STAGE_A(0, 0, 1, w); STAGE_A(0, 0, 1, w + 8);
    STAGE_B(1, 64, 0, w); STAGE_B(1, 64, 0, w + 8);
    STAGE_B(1, 64, 1, w); STAGE_B(1, 64, 1, w + 8);
    asm volatile("s_waitcnt vmcnt(4)" ::: "memory");
    __builtin_amdgcn_s_barrier();

    for (int i = 0; i < 8; ++i) {
        const bool pf   = (i < 7);
        const int kbO1 = (2 * i + 1) << 6;   // current odd tile (A staged P0,P1)
        const int kbE2 = (2 * i + 2) << 6;   // next even tile
        const int kbO2 = (2 * i + 3) << 6;   // next odd tile

        s16x8 a0[4][2], a1[4][2], b0[2][2], b1[2][2];

        // ===================== even tile (buf0) =====================
        // --- P0: ds a0,b0; stage A(2i+1).h0 -> buf1; MFMA Q0
        #pragma unroll
        for (int mf = 0; mf < 4; ++mf)
            #pragma unroll
            for (int ks = 0; ks < 2; ++ks)
                a0[mf][ks] = *(const s16x8*)
                    &As[0][(((wr * 8 + mf) * 2 + ks) << 9) + roff];
        #pragma unroll
        for (int nf = 0; nf < 2; ++nf)
            #pragma unroll
            for (int ks = 0; ks < 2; ++ks)
                b0[nf][ks] = *(const s16x8*)
                    &Bs[0][(((wc * 4 + nf) * 2 + ks) << 9) + roff];
        STAGE_A(1, kbO1, 0, w); STAGE_A(1, kbO1, 0, w + 8);
        __builtin_amdgcn_s_barrier();
        __builtin_amdgcn_s_setprio(1);
        #pragma unroll
        for (int mf = 0; mf < 4; ++mf)
            #pragma unroll
            for (int nf = 0; nf < 2; ++nf)
                #pragma unroll
                for (int ks = 0; ks < 2; ++ks)
                    acc[mf][nf] = MFMA_BF16(a0[mf][ks], b0[nf][ks],
                                            acc[mf][nf], 0, 0, 0);
        __builtin_amdgcn_s_setprio(0);
        __builtin_amdgcn_s_barrier();

        // --- P1: ds b1; stage A(2i+1).h1 -> buf1; MFMA Q1
        #pragma unroll
        for (int nf = 0; nf < 2; ++nf)
            #pragma unroll
            for (int ks = 0; ks < 2; ++ks)
                b1[nf][ks] = *(const s16x8*)
                    &Bs[0][(((wc * 4 + 2 + nf) * 2 + ks) << 9) + roff];
        STAGE_A(1, kbO1, 1, w); STAGE_A(1, kbO1, 1, w + 8);
        __builtin_amdgcn_s_barrier();
        __builtin_amdgcn_s_setprio(1);
        #pragma unroll
        for (int mf = 0; mf < 4; ++mf)
            #pragma unroll
            for (int nf = 0; nf < 2; ++nf)
                #pragma unroll
                for (int ks = 0; ks < 2; ++ks)
                    acc[mf][2 + nf] = MFMA_BF16(a0[mf][ks], b1[nf][ks],
                                                acc[mf][2 + nf], 0, 0, 0);
        __builtin_amdgcn_s_setprio(0);
        __builtin_amdgcn_s_barrier();

        // --- P2: ds a1; stage B(2i+2).h0 -> buf0; MFMA Q2
        #pragma unroll
        for (int mf = 0; mf < 4; ++mf)
            #pragma unroll
            for (int ks = 0; ks < 2; ++ks)
                a1[mf][ks] = *(const s16x8*)
                    &As[0][(((wr * 8 + 4 + mf) * 2 + ks) << 9) + roff];
        if (pf) { STAGE_B(0, kbE2, 0, w); STAGE_B(0, kbE2, 0, w + 8); }
        __builtin_amdgcn_s_barrier();
        __builtin_amdgcn_s_setprio(1);
        #pragma unroll
        for (int mf = 0; mf < 4; ++mf)
            #pragma unroll
            for (int nf = 0; nf < 2; ++nf)
                #pragma unroll
                for (int ks = 0; ks < 2; ++ks)
                    acc[4 + mf][nf] = MFMA_BF16(a1[mf][ks], b0[nf][ks],
                                                acc[4 + mf][nf], 0, 0, 0);
        __builtin_amdgcn_s_setprio(0);
        __builtin_amdgcn_s_barrier();

        // --- P3: stage B(2i+2).h1 -> buf0; MFMA Q3; gate tile 2i+1
        if (pf) { STAGE_B(0, kbE2, 1, w); STAGE_B(0, kbE2, 1, w + 8); }
        __builtin_amdgcn_s_barrier();
        __builtin_amdgcn_s_setprio(1);
        #pragma unroll
        for (int mf = 0; mf < 4; ++mf)
            #pragma unroll
            for (int nf = 0; nf < 2; ++nf)
                #pragma unroll
                for (int ks = 0; ks < 2; ++ks)
                    acc[4 + mf][2 + nf] = MFMA_BF16(a1[mf][ks], b1[nf][ks],
                                                    acc[4 + mf][2 + nf], 0, 0, 0);
        __builtin_amdgcn_s_setprio(0);
        if (pf) asm volatile("s_waitcnt vmcnt(4)" ::: "memory");
        else    asm volatile("s_waitcnt vmcnt(0)" ::: "memory");
        __builtin_amdgcn_s_barrier();
        __builtin_amdgcn_sched_barrier(0);

        // ===================== odd tile (buf1) =====================
        // --- P4: ds a0,b0; stage A(2i+2).h0 -> buf0; MFMA Q0
        #pragma unroll
        for (int mf = 0; mf < 4; ++mf)
            #pragma unroll
            for (int ks = 0; ks < 2; ++ks)
                a0[mf][ks] = *(const s16x8*)
                    &As[1][(((wr * 8 + mf) * 2 + ks) << 9) + roff];
        #pragma unroll
        for (int nf = 0; nf < 2; ++nf)
            #pragma unroll
            for (int ks = 0; ks < 2; ++ks)
                b0[nf][ks] = *(const s16x8*)
                    &Bs[1][(((wc * 4 + nf) * 2 + ks) << 9) + roff];
        if (pf) { STAGE_A(0, kbE2, 0, w); STAGE_A(0, kbE2, 0, w + 8); }
        __builtin_amdgcn_s_barrier();
        __builtin_amdgcn_s_setprio(1);
        #pragma unroll
        for (int mf = 0; mf < 4; ++mf)
            #pragma unroll
            for (int nf = 0; nf < 2; ++nf)
                #pragma unroll
                for (int ks = 0; ks < 2; ++ks)
                    acc[mf][nf] = MFMA_BF16(a0[mf][ks], b0[nf][ks],
                                            acc[mf][nf], 0, 0, 0);
        __builtin_amdgcn_s_setprio(0);
        __builtin_amdgcn_s_barrier();

        // --- P5: ds b1; stage A(2i+2).h1 -> buf0; MFMA Q1
        #pragma unroll
        for (int nf = 0; nf < 2; ++nf)
            #pragma unroll
            for (int ks = 0; ks < 2; ++ks)
                b1[nf][ks] = *(const s16x8*)
                    &Bs[1][(((wc * 4 + 2 + nf) * 2 + ks) << 9) + roff];
        if (pf) { STAGE_A(0, kbE2, 1, w); STAGE_A(0, kbE2, 1, w + 8); }
        __builtin_amdgcn_s_barrier();
        __builtin_amdgcn_s_setprio(1);
        #pragma unroll
        for (int mf = 0; mf < 4; ++mf)
            #pragma unroll
            for (int nf = 0; nf < 2; ++nf)
                #pragma unroll
                for (int ks = 0; ks < 2; ++ks)
                    acc[mf][2 + nf] = MFMA_BF16(a0[mf][ks], b1[nf][ks],
                                                acc[mf][2 + nf], 0, 0, 0);
        __builtin_amdgcn_s_setprio(0);
        __builtin_amdgcn_s_barrier();

        // --- P6: ds a1; stage B(2i+3).h0 -> buf1; MFMA Q2
        #pragma unroll
        for (int mf = 0; mf < 4; ++mf)
            #pragma unroll
            for (int ks = 0; ks < 2; ++ks)
                a1[mf][ks] = *(const s16x8*)
                    &As[1][(((wr * 8 + 4 + mf) * 2 + ks) << 9) + roff];
        if (pf) { STAGE_B(1, kbO2, 0, w); STAGE_B(1, kbO2, 0, w + 8); }
        __builtin_amdgcn_s_barrier();
        __builtin_amdgcn_s_setprio(1);
        #pragma unroll
        for (int mf = 0; mf < 4; ++mf)
            #pragma unroll
            for (int nf = 0; nf < 2; ++nf)
                #pragma unroll
                for (int ks = 0; ks < 2; ++ks)
                    acc[4 + mf][nf] = MFMA_BF16(a1[mf][ks], b0[nf][ks],
                                                acc[4 + mf][nf], 0, 0, 0);
        __builtin_amdgcn_s_setprio(0);
        __builtin_amdgcn_s_barrier();

        // --- P7: stage B(2i+3).h1 -> buf1; MFMA Q3; gate tile 2i+2
        if (pf) { STAGE_B(1, kbO2, 1, w); STAGE_B(1, kbO2, 1, w + 8); }
        __builtin_amdgcn_s_barrier();
        __builtin_amdgcn_s_setprio(1);
        #pragma unroll
        for (int mf = 0; mf < 4; ++mf)
            #pragma unroll
            for (int nf = 0; nf < 2; ++nf)
                #pragma unroll
                for (int ks = 0; ks < 2; ++ks)
                    acc[4 + mf][2 + nf] = MFMA_BF16(a1[mf][ks], b1[nf][ks],
                                                    acc[4 + mf][2 + nf], 0, 0, 0);
        __builtin_amdgcn_s_setprio(0);
        if (pf) {
            asm volatile("s_waitcnt vmcnt(4)" ::: "memory");
            __builtin_amdgcn_s_barrier();
            __builtin_amdgcn_sched_barrier(0);
        }
    }

    // ---- epilogue: score partial = sum_cols Va*tanh(q+e); reduce; atomic.
    // C/D mapping: col = lane&15, row = (lane>>4)*4 + j
    const int b = M0 >> 11;   // 256-row tile never crosses 2048-row batch
    const float* qrow = qe + (size_t)b * HDIM;
    #pragma unroll
    for (int mf = 0; mf < 8; ++mf) {
        float part[4] = {0.f, 0.f, 0.f, 0.f};
        #pragma unroll
        for (int nf = 0; nf < 4; ++nf) {
            const int c    = N0 + wc * 64 + nf * 16 + (lane & 15);
            const float va = Va[c];
            const float qv = qrow[c];
            #pragma unroll
            for (int j = 0; j < 4; ++j) {
                const float x = qv + acc[mf][nf][j];
                const float e = __expf(2.0f * x);
                part[j] += va * (1.0f - 2.0f / (e + 1.0f));   // tanh(x)
            }
        }
        #pragma unroll
        for (int j = 0; j < 4; ++j)
            #pragma unroll
            for (int off = 1; off < 16; off <<= 1)
                part[j] += __shfl_xor(part[j], off);
        if ((lane & 15) == 0) {
            const int rr = M0 + wr * 128 + mf * 16 + (lane >> 4) * 4;
            #pragma unroll
            for (int j = 0; j < 4; ++j) atomicAdd(&scores[rr + j], part[j]);
        }
    }
}

// ---------------------------------------------------------------------------
// Kernel 2 (fallback): reg-staged f32 scores GEMM (round-1 proven).
// ---------------------------------------------------------------------------
__global__ __launch_bounds__(256) void score_gemm_f32_kernel(
    const float* __restrict__ keys, const float* __restrict__ Ua,
    const float* __restrict__ qe,   const float* __restrict__ Va,
    float* __restrict__ scores)
{
    __shared__ bf16 Asf[128][40];
    __shared__ bf16 Bsf[128][40];

    const int tid  = threadIdx.x;
    const int lane = tid & 63;
    const int wid  = tid >> 6;
    const int wr   = wid >> 1, wc = wid & 1;
    const int n0   = blockIdx.x * 128;
    const int m0   = blockIdx.y * 128;

    const int srow  = tid >> 1;
    const int shalf = tid & 1;
    const float* gA = keys + (size_t)(m0 + srow) * FDIM + shalf * 16;
    const float* gB = Ua   + (size_t)(n0 + srow) * FDIM + shalf * 16;

    f32x4 acc[4][4];
    #pragma unroll
    for (int m = 0; m < 4; ++m)
        #pragma unroll
        for (int n = 0; n < 4; ++n) acc[m][n] = (f32x4){0.f, 0.f, 0.f, 0.f};

    float4 ra[4], rbv[4];
    #pragma unroll
    for (int i = 0; i < 4; ++i) {
        ra[i]  = ((const float4*)gA)[i];
        rbv[i] = ((const float4*)gB)[i];
    }

    for (int kt = 0; kt < 32; ++kt) {
        __syncthreads();
        {
            union { bf16 h[16]; s16x8 v[2]; } ua, ub;
            #pragma unroll
            for (int i = 0; i < 4; ++i) {
                const float* fa = (const float*)&ra[i];
                const float* fb = (const float*)&rbv[i];
                #pragma unroll
                for (int j = 0; j < 4; ++j) {
                    ua.h[i*4+j] = __float2bfloat16(fa[j]);
                    ub.h[i*4+j] = __float2bfloat16(fb[j]);
                }
            }
            *(s16x8*)&Asf[srow][shalf*16]     = ua.v[0];
            *(s16x8*)&Asf[srow][shalf*16 + 8] = ua.v[1];
            *(s16x8*)&Bsf[srow][shalf*16]     = ub.v[0];
            *(s16x8*)&Bsf[srow][shalf*16 + 8] = ub.v[1];
        }
        __syncthreads();

        if (kt + 1 < 32) {
            const float* pa = gA + (kt + 1) * 32;
            const float* pb = gB + (kt + 1) * 32;
            #pragma unroll
            for (int i = 0; i < 4; ++i) {
                ra[i]  = ((const float4*)pa)[i];
                rbv[i] = ((const float4*)pb)[i];
            }
        }

        s16x8 af[4], bfr[4];
        #pragma unroll
        for (int m = 0; m < 4; ++m)
            af[m] = *(const s16x8*)&Asf[wr*64 + m*16 + (lane & 15)][(lane >> 4) * 8];
        #pragma unroll
        for (int n = 0; n < 4; ++n)
            bfr[n] = *(const s16x8*)&Bsf[wc*64 + n*16 + (lane & 15)][(lane >> 4) * 8];
        #pragma unroll
        for (int m = 0; m < 4; ++m)
            #pragma unroll
            for (int n = 0; n < 4; ++n)
                acc[m][n] = MFMA_BF16(af[m], bfr[n], acc[m][n], 0, 0, 0);
    }

    const int b = m0 >> 11;
    const float* qrow = qe + (size_t)b * HDIM;
    #pragma unroll
    for (int m = 0; m < 4; ++m) {
        float part[4] = {0.f, 0.f, 0.f, 0.f};
        #pragma unroll
        for (int n = 0; n < 4; ++n) {
            const int c    = n0 + wc*64 + n*16 + (lane & 15);
            const float va = Va[c];
            const float qv = qrow[c];
            #pragma unroll
            for (int j = 0; j < 4; ++j) {
                const float x = qv + acc[m][n][j];
                const float e = __expf(2.0f * x);
                part[j] += va * (1.0f - 2.0f / (e + 1.0f));
            }
        }
        #pragma unroll
        for (int j = 0; j < 4; ++j)
            #pragma unroll
            for (int off = 1; off < 16; off <<= 1)
                part[j] += __shfl_xor(part[j], off);
        if ((lane & 15) == 0) {
            const int rr = m0 + wr*64 + m*16 + (lane >> 4) * 4;
            #pragma unroll
            for (int j = 0; j < 4; ++j) atomicAdd(&scores[rr + j], part[j]);
        }
    }
}

// ---------------------------------------------------------------------------
// Kernel 3: softmax over T=2048, in place. One block per b.
// ---------------------------------------------------------------------------
__global__ __launch_bounds__(256) void softmax_kernel(float* __restrict__ sw)
{
    const int b    = blockIdx.x;
    const int tid  = threadIdx.x;
    const int lane = tid & 63, wid = tid >> 6;
    __shared__ float red[8];

    float v[8];
    float m = -3.4e38f;
    #pragma unroll
    for (int i = 0; i < 8; ++i) {
        v[i] = sw[b * TDIM + i * 256 + tid];
        m = fmaxf(m, v[i]);
    }
    #pragma unroll
    for (int off = 32; off > 0; off >>= 1) m = fmaxf(m, __shfl_xor(m, off));
    if (lane == 0) red[wid] = m;
    __syncthreads();
    m = fmaxf(fmaxf(red[0], red[1]), fmaxf(red[2], red[3]));

    float s = 0.f;
    #pragma unroll
    for (int i = 0; i < 8; ++i) { v[i] = __expf(v[i] - m); s += v[i]; }
    #pragma unroll
    for (int off = 32; off > 0; off >>= 1) s += __shfl_xor(s, off);
    if (lane == 0) red[4 + wid] = s;
    __syncthreads();
    s = (red[4] + red[5]) + (red[6] + red[7]);

    const float inv = 1.0f / s;
    #pragma unroll
    for (int i = 0; i < 8; ++i) sw[b * TDIM + i * 256 + tid] = v[i] * inv;
}

// ---------------------------------------------------------------------------
// Kernel 4: context[b,f] = sum_t w[b,t]*keys[b,t,f].  bf16-keys variant.
// ---------------------------------------------------------------------------
__global__ __launch_bounds__(256) void context_bf16_kernel(
    const bf16* __restrict__ keys, const float* __restrict__ w,
    float* __restrict__ ctx)
{
    const int tc  = blockIdx.x;   // 0..15 (128 t each)
    const int b   = blockIdx.y;
    const int tid = threadIdx.x;
    __shared__ float ws_[128];
    if (tid < 128) ws_[tid] = w[b * TDIM + tc * 128 + tid];
    __syncthreads();

    const bf16* kp = keys + ((size_t)b * TDIM + (size_t)tc * 128) * FDIM + tid * 4;
    float4 acc = {0.f, 0.f, 0.f, 0.f};
    #pragma unroll 8
    for (int t = 0; t < 128; ++t) {
        const short4 kv = *(const short4*)(kp + (size_t)t * FDIM);
        const float wt = ws_[t];
        acc.x += wt * __uint_as_float(((unsigned)(unsigned short)kv.x) << 16);
        acc.y += wt * __uint_as_float(((unsigned)(unsigned short)kv.y) << 16);
        acc.z += wt * __uint_as_float(((unsigned)(unsigned short)kv.z) << 16);
        acc.w += wt * __uint_as_float(((unsigned)(unsigned short)kv.w) << 16);
    }
    float* cp = ctx + (size_t)b * FDIM + tid * 4;
    atomicAdd(cp + 0, acc.x); atomicAdd(cp + 1, acc.y);
    atomicAdd(cp + 2, acc.z); atomicAdd(cp + 3, acc.w);
}

// f32-keys fallback variant
__global__ __launch_bounds__(256) void context_f32_kernel(
    const float* __restrict__ keys, const float* __restrict__ w,
    float* __restrict__ ctx)
{
    const int tc  = blockIdx.x;
    const int b   = blockIdx.y;
    const int tid = threadIdx.x;
    __shared__ float ws_[128];
    if (tid < 128) ws_[tid] = w[b * TDIM + tc * 128 + tid];
    __syncthreads();

    const float* kp = keys + ((size_t)b * TDIM + (size_t)tc * 128) * FDIM + tid * 4;
    float4 acc = {0.f, 0.f, 0.f, 0.f};
    #pragma unroll 8
    for (int t = 0; t < 128; ++t) {
        const float4 kv = *(const float4*)(kp + (size_t)t * FDIM);
        const float wt = ws_[t];
        acc.x += wt * kv.x; acc.y += wt * kv.y;
        acc.z += wt * kv.z; acc.w += wt * kv.w;
    }
    float* cp = ctx + (size_t)b * FDIM + tid * 4;
    atomicAdd(cp + 0, acc.x); atomicAdd(cp + 1, acc.y);
    atomicAdd(cp + 2, acc.z); atomicAdd(cp + 3, acc.w);
}

// ---------------------------------------------------------------------------
extern "C" void kernel_launch(void* const* d_in, const int* in_sizes, int n_in,
                              void* d_out, int out_size, void* d_ws, size_t ws_size,
                              hipStream_t stream)
{
    const float* query = (const float*)d_in[0];
    const float* keys  = (const float*)d_in[1];
    const float* Wa_w  = (const float*)d_in[2];
    const float* Wa_b  = (const float*)d_in[3];
    const float* Ua_w  = (const float*)d_in[4];
    const float* Ua_b  = (const float*)d_in[5];
    const float* Va_w  = (const float*)d_in[6];
    // d_in[7] = Va_b: softmax is shift-invariant -> no effect on outputs.

    float* out = (float*)d_out;
    float* ctx = out;                 // 32*1024 floats; doubles as q_eff scratch
    float* sw  = out + BDIM * HDIM;   // 32*2048 floats; scores -> weights

    const size_t needA = (size_t)MTOT * FDIM * sizeof(bf16);   // 128 MB
    const size_t needB = (size_t)HDIM * FDIM * sizeof(bf16);   //   2 MB
    const bool fast = ws_size >= needA + needB;

    hipMemsetAsync(sw, 0, (size_t)BDIM * TDIM * sizeof(float), stream);
    qeff_kernel<<<dim3(BDIM * HDIM / 4), 256, 0, stream>>>(query, Wa_w, Wa_b, Ua_b, ctx);

    if (fast) {
        bf16* Ab = (bf16*)d_ws;
        bf16* Bb = Ab + (size_t)MTOT * FDIM;
        cvt_bf16_kernel<<<dim3(2048), 256, 0, stream>>>(keys, Ab, MTOT * FDIM / 8);
        cvt_bf16_kernel<<<dim3(512),  256, 0, stream>>>(Ua_w, Bb, HDIM * FDIM / 8);
        score_gemm_256_kernel<<<dim3(1024), 512, 0, stream>>>(Ab, Bb, ctx, Va_w, sw);
        softmax_kernel<<<dim3(BDIM), 256, 0, stream>>>(sw);
        hipMemsetAsync(ctx, 0, (size_t)BDIM * HDIM * sizeof(float), stream);
        context_bf16_kernel<<<dim3(16, BDIM), 256, 0, stream>>>(Ab, sw, ctx);
    } else {
        score_gemm_f32_kernel<<<dim3(HDIM / 128, MTOT / 128), 256, 0, stream>>>(
            keys, Ua_w, ctx, Va_w, sw);
        softmax_kernel<<<dim3(BDIM), 256, 0, stream>>>(sw);
        hipMemsetAsync(ctx, 0, (size_t)BDIM * HDIM * sizeof(float), stream);
        context_f32_kernel<<<dim3(16, BDIM), 256, 0, stream>>>(keys, sw, ctx);
    }
}